// Round 15
// baseline (129.055 us; speedup 1.0000x reference)
//
#include <hip/hip_runtime.h>
#include <math.h>

#define NROWS 32768
#define NCODE 1024
#define GAP_THRESH 1.5e-4f  // exact fp32 gap; emulation err ~1e-5, np-ref rounding ~2e-5
#define FLAG_TAG_SHIFT 30   // flags[row]>>30==1 <=> ambiguous (rejects 0xAA poison AND 0)

typedef __attribute__((ext_vector_type(8))) short bf16x8;   // 8 bf16 = 4 VGPRs
typedef __attribute__((ext_vector_type(4))) float f32x4;    // MFMA acc

__device__ __forceinline__ unsigned short bf16_rne(float f) {
    unsigned u = __float_as_uint(f);
    unsigned r = u + 0x7FFFu + ((u >> 16) & 1u);
    return (unsigned short)(r >> 16);
}

// ---------------------------------------------------------------------------
// main: 512 blocks x 512 threads = 64 rows x ALL 1024 codes. Prep folded in
// (r13-proven): each block converts raw fp32 cb chunks (128 codes, 32 KB)
// regs -> split-bf16 frags in-LDS; cn4 via quad-shfl. Init-free globals:
// tagged flags / sumsqP / entPartial / ticket=0 by block 0.
// ---------------------------------------------------------------------------
__global__ __launch_bounds__(512, 4) void vq_main(
    const float* __restrict__ x, const float* __restrict__ cb,
    float* __restrict__ out, float* __restrict__ entPartial,
    unsigned* __restrict__ flags, float* __restrict__ sumsqP,
    unsigned* __restrict__ ticket)
{
    __shared__ __align__(16) unsigned char Bb[2][32768];
    __shared__ float cn4L[2][128];
    __shared__ unsigned scrE[1024];        // per-block per-code min dist (raw bits)
    __shared__ float mD1[128], mD2[128];   // [row 0..63][half 0..1]
    __shared__ int   mI1[128];
    __shared__ int   tokS[64];
    __shared__ float redS[8];

    const int tid = threadIdx.x;
    const int lane = tid & 63;
    const int wi = tid >> 6;         // 0..7
    const int g = wi >> 1;           // row group 0..3 (16 rows each)
    const int h = wi & 1;            // code half: ct tiles 4h..4h+3
    const int ln15 = lane & 15;
    const int q = lane >> 4;
    const int row0 = blockIdx.x * 64;
    const int rot = blockIdx.x & 7;  // 8 chunks of 128 codes

    if (blockIdx.x == 0 && tid == 0) *ticket = 0u;

    // init scrE to +inf bits
    scrE[tid] = 0x7F800000u;
    scrE[512 + tid] = 0x7F800000u;

    // stage: convert 16 fp32 (one quarter code row) -> hi/lo frags + cn4
    auto stage = [&](int bufIdx, float4 v0, float4 v1, float4 v2, float4 v3) {
        float f[16] = {v0.x,v0.y,v0.z,v0.w, v1.x,v1.y,v1.z,v1.w,
                       v2.x,v2.y,v2.z,v2.w, v3.x,v3.y,v3.z,v3.w};
        float ss = 0.f;
        #pragma unroll
        for (int j = 0; j < 16; j++) ss = fmaf(f[j], f[j], ss);
        ss += __shfl_xor(ss, 1);
        ss += __shfl_xor(ss, 2);        // quad (same code) full sumsq
        const int lc = tid >> 2, p = tid & 3;
        const int ct = lc >> 4, cl = lc & 15;
        const int half = p >> 1, gp = p & 1;
        unsigned char* tb = Bb[bufIdx] + (ct >> 2)*16384 + (ct & 3)*4096;
        #pragma unroll
        for (int sub = 0; sub < 2; sub++) {
            unsigned short h8[8] __attribute__((aligned(16)));
            unsigned short l8[8] __attribute__((aligned(16)));
            #pragma unroll
            for (int j = 0; j < 8; j++) {
                float ff = f[sub*8 + j];
                unsigned short hi = bf16_rne(ff);
                h8[j] = hi;
                l8[j] = bf16_rne(ff - __uint_as_float((unsigned)hi << 16));
            }
            int off = ((gp*2 + sub)*16 + cl) * 16;
            *(uint4*)(tb + half*1024 + off)        = *(const uint4*)h8;   // q = half
            *(uint4*)(tb + 2048 + half*1024 + off) = *(const uint4*)l8;   // q = 2+half
        }
        if (p == 0) cn4L[bufIdx][lc] = ss + 4.0f;
    };

    // preload chunk 'rot' raw fp32 into regs (coalesced: quad covers one code)
    float4 v0, v1, v2, v3;
    {
        const float4* ls = (const float4*)(cb + ((size_t)rot*128 + (tid>>2))*64 + (tid&3)*16);
        v0 = ls[0]; v1 = ls[1]; v2 = ls[2]; v3 = ls[3];
    }

    // ---- A: 16 rows fp32 -> split-bf16 frags in regs; row norms via shfl ----
    bf16x8 Ah0, Ah1, Al0, Al1;
    float xnm4[4];
    {
        const float* xr = x + (size_t)(row0 + g*16 + ln15) * 64 + q * 8;
        float4 f0 = *(const float4*)xr;
        float4 f1 = *(const float4*)(xr + 4);
        float4 f2 = *(const float4*)(xr + 32);
        float4 f3 = *(const float4*)(xr + 36);
        float fa[8] = {f0.x,f0.y,f0.z,f0.w,f1.x,f1.y,f1.z,f1.w};
        float fb[8] = {f2.x,f2.y,f2.z,f2.w,f3.x,f3.y,f3.z,f3.w};
        unsigned short hh8[8] __attribute__((aligned(16)));
        unsigned short ll8[8] __attribute__((aligned(16)));
        unsigned short h28[8] __attribute__((aligned(16)));
        unsigned short l28[8] __attribute__((aligned(16)));
        float ss = 0.f;
        #pragma unroll
        for (int j = 0; j < 8; j++) {
            ss += fa[j]*fa[j] + fb[j]*fb[j];
            unsigned short hh = bf16_rne(fa[j]);
            hh8[j] = hh; ll8[j] = bf16_rne(fa[j] - __uint_as_float((unsigned)hh << 16));
            hh = bf16_rne(fb[j]);
            h28[j] = hh; l28[j] = bf16_rne(fb[j] - __uint_as_float((unsigned)hh << 16));
        }
        Ah0 = *(const bf16x8*)hh8; Al0 = *(const bf16x8*)ll8;
        Ah1 = *(const bf16x8*)h28; Al1 = *(const bf16x8*)l28;
        ss += __shfl_xor(ss, 16);
        ss += __shfl_xor(ss, 32);            // ||x_row(ln15)||^2
        #pragma unroll
        for (int r = 0; r < 4; r++)
            xnm4[r] = __shfl(ss, (q << 2) | r, 64) - 4.0f;  // xn(row q*4+r) - 4
    }

    // convert+write chunk 'rot' into Bb[0]
    stage(0, v0, v1, v2, v3);

    float d1[4], d2[4];
    int   i1[4];
    #pragma unroll
    for (int r = 0; r < 4; r++) { d1[r] = INFINITY; d2[r] = INFINITY; i1[r] = 0; }

    // ---- chunk loop: 8 chunks x 128 codes (rotated order) ----
    for (int s = 0; s < 8; s++) {
        __syncthreads();   // Bb[s&1]+cn4L[s&1] staged; Bb[nb] free
        const int cb_ = s & 1, nb = (s + 1) & 1;
        const int cphys = (s + rot) & 7;
        if (s < 7) {       // prefetch next raw chunk into regs
            const int cnx = (s + 1 + rot) & 7;
            const float4* ls = (const float4*)(cb + ((size_t)cnx*128 + (tid>>2))*64 + (tid&3)*16);
            v0 = ls[0]; v1 = ls[1]; v2 = ls[2]; v3 = ls[3];
        }
        const unsigned char* buf = Bb[cb_];
        #pragma unroll
        for (int lct = 0; lct < 4; lct++) {
            const int ct = 4*h + lct;                       // 0..7 within 128-code chunk
            const unsigned char* tb = buf + (ct >> 2)*16384 + (ct & 3)*4096;
            bf16x8 Bh0 = *(const bf16x8*)(tb +    0 + lane*16);
            bf16x8 Bh1 = *(const bf16x8*)(tb + 1024 + lane*16);
            bf16x8 Bl0 = *(const bf16x8*)(tb + 2048 + lane*16);
            bf16x8 Bl1 = *(const bf16x8*)(tb + 3072 + lane*16);
            float cn4v = cn4L[cb_][ct*16 + ln15];
            int kid = cphys*128 + ct*16 + ln15;
            f32x4 z = {0.f, 0.f, 0.f, 0.f};
            f32x4 acc0 = __builtin_amdgcn_mfma_f32_16x16x32_bf16(Ah0, Bh0, z, 0, 0, 0);
            f32x4 acc1 = __builtin_amdgcn_mfma_f32_16x16x32_bf16(Ah1, Bh1, z, 0, 0, 0);
            acc0 = __builtin_amdgcn_mfma_f32_16x16x32_bf16(Ah0, Bl0, acc0, 0, 0, 0);
            acc1 = __builtin_amdgcn_mfma_f32_16x16x32_bf16(Ah1, Bl1, acc1, 0, 0, 0);
            acc0 = __builtin_amdgcn_mfma_f32_16x16x32_bf16(Al0, Bh0, acc0, 0, 0, 0);
            acc1 = __builtin_amdgcn_mfma_f32_16x16x32_bf16(Al1, Bh1, acc1, 0, 0, 0);
            float cminv = INFINITY;
            #pragma unroll
            for (int r = 0; r < 4; r++) {
                float sdot = acc0[r] + acc1[r];
                float wv = fmaf(sdot, -2.0f, cn4v);   // 4 + cn - 2s  (>0)
                bool lt = wv < d1[r];
                d2[r] = lt ? d1[r] : fminf(d2[r], wv);
                i1[r] = lt ? kid   : i1[r];
                d1[r] = lt ? wv    : d1[r];
                cminv = fminf(cminv, wv + xnm4[r]);   // full dist (entropy)
            }
            cminv = fminf(cminv, __shfl_xor(cminv, 16));
            cminv = fminf(cminv, __shfl_xor(cminv, 32));   // min over wave's 16 rows
            if (q == lct) atomicMin(&scrE[kid], __float_as_uint(cminv));
        }
        if (s < 7) stage(nb, v0, v1, v2, v3);   // convert+write next chunk
    }
    __syncthreads();   // scrE complete; all compute done

    // ---- butterfly exact top-2 merge across the 16 code-column lanes ----
    #pragma unroll
    for (int d = 1; d < 16; d <<= 1) {
        #pragma unroll
        for (int r = 0; r < 4; r++) {
            float od1 = __shfl_xor(d1[r], d);
            int   oi1 = __shfl_xor(i1[r], d);
            float od2 = __shfl_xor(d2[r], d);
            bool take = (od1 < d1[r]) || (od1 == d1[r] && oi1 < i1[r]);
            float loser = take ? d1[r] : od1;
            d2[r] = fminf(fminf(d2[r], od2), loser);
            d1[r] = take ? od1 : d1[r];
            i1[r] = take ? oi1 : i1[r];
        }
    }
    if (ln15 == 0) {
        #pragma unroll
        for (int r = 0; r < 4; r++) {
            int idx = (g*16 + q*4 + r) * 2 + h;
            mD1[idx] = d1[r]; mI1[idx] = i1[r]; mD2[idx] = d2[r];
        }
    }
    __syncthreads();   // per-half candidates staged

    // ---- exact cross-half merge -> token + tagged ambiguity flag ----
    if (tid < 64) {
        float a1 = mD1[tid*2],   b1 = mD1[tid*2+1];
        int   ai = mI1[tid*2],   bi = mI1[tid*2+1];
        float a2 = mD2[tid*2],   b2 = mD2[tid*2+1];
        bool ta = (a1 < b1) || (a1 == b1 && ai < bi);
        float D1 = ta ? a1 : b1;
        int   I1 = ta ? ai : bi;
        float D2 = ta ? fminf(a2, b1) : fminf(b2, a1);
        tokS[tid] = I1;
        if (D2 - D1 < GAP_THRESH)
            flags[row0 + tid] = (1u << FLAG_TAG_SHIFT) | (unsigned)I1;
    }

    // ---- entropy partials: coalesced per-block row (always fully written) ----
    entPartial[(size_t)blockIdx.x * 1024 + tid]       = __uint_as_float(scrE[tid]);
    entPartial[(size_t)blockIdx.x * 1024 + 512 + tid] = __uint_as_float(scrE[512 + tid]);
    __syncthreads();   // tokS ready

    // ---- emb gather + sumsq -> sumsqP[block] ----
    {
        float acc2 = 0.f;
        #pragma unroll
        for (int uu = 0; uu < 2; uu++) {
            int u = uu*512 + tid;
            int row = u >> 4, c4 = u & 15;
            int tok = tokS[row];
            float4 c = ((const float4*)(cb + (size_t)tok*64))[c4];
            float4 xx = ((const float4*)(x + (size_t)(row0 + row)*64))[c4];
            ((float4*)(out + (size_t)(row0 + row)*64))[c4] = c;
            float dx = c.x-xx.x, dy = c.y-xx.y, dz = c.z-xx.z, dw = c.w-xx.w;
            acc2 += dx*dx + dy*dy + dz*dz + dw*dw;
        }
        #pragma unroll
        for (int o = 32; o > 0; o >>= 1) acc2 += __shfl_down(acc2, o);
        if (lane == 0) redS[wi] = acc2;
        __syncthreads();
        if (tid == 0) {
            float t = 0.f;
            #pragma unroll
            for (int w = 0; w < 8; w++) t += redS[w];
            sumsqP[blockIdx.x] = t;
        }
    }
}

// ---------------------------------------------------------------------------
// tail: 64 blocks x 256 threads.
// (A) coalesced entropy reduce (r13-proven) -> partial2[4][1024].
// (B) flags scan + fp64 fixup with cb staged through LDS in 4 coalesced 64-KB
//     batches (r14-proven fix for the ~50 us uncoalesced-read floor).
// (C) last-ticket block assembles the loss (r13-proven).
// ---------------------------------------------------------------------------
__global__ __launch_bounds__(256) void vq_tail(
    const float* __restrict__ x, const float* __restrict__ cb,
    float* __restrict__ out, const float* __restrict__ entPartial,
    const unsigned* __restrict__ flags, const float* __restrict__ sumsqP,
    float* __restrict__ deltaP, float* __restrict__ partial2,
    unsigned* __restrict__ ticket, float* __restrict__ out_loss)
{
    __shared__ __align__(16) float cbS[16384];   // 64 KB: 256 codes x 64 dims
    __shared__ double xs[64];
    __shared__ double bd[256];
    __shared__ int    bi[256];
    __shared__ float  scrR[256];
    __shared__ int    listRow[32], listTok[32];
    __shared__ int    lcnt;
    __shared__ double deltaS;
    __shared__ unsigned lastS;
    __shared__ float redS[4], redS2[4];

    const int tid = threadIdx.x;
    const int lane = tid & 63;
    const int w = tid >> 6;
    const int b = blockIdx.x;

    if (tid == 0) { lcnt = 0; deltaS = 0.0; }

    // ---- A: entropy 512 block-rows -> 4 rowGroups (coalesced 256B reads) ----
    {
        int rg = b >> 4, cgp = b & 15;
        float m = INFINITY;
        #pragma unroll 8
        for (int i = 0; i < 32; i++)
            m = fminf(m, entPartial[(size_t)(rg*128 + w*32 + i)*1024 + cgp*64 + lane]);
        scrR[w*64 + lane] = m;
    }
    __syncthreads();
    if (w == 0) {
        float m = fminf(fminf(scrR[lane], scrR[64+lane]),
                        fminf(scrR[128+lane], scrR[192+lane]));
        partial2[(size_t)(b >> 4)*1024 + (b & 15)*64 + lane] = m;
    }

    // ---- B: scan tagged flags, compact, coalesced fp64 fixup ----
    #pragma unroll
    for (int u = 0; u < 2; u++) {
        int row = b*512 + u*256 + tid;
        unsigned f = flags[row];
        if ((f >> FLAG_TAG_SHIFT) == 1u) {     // rejects 0xAA poison (0b10) and 0
            int idx = atomicAdd(&lcnt, 1);
            if (idx < 32) { listRow[idx] = row; listTok[idx] = (int)(f & 1023u); }
        }
    }
    __syncthreads();
    int nfix = lcnt < 32 ? lcnt : 32;
    for (int i = 0; i < nfix; i++) {
        int row = listRow[i], oldk = listTok[i];
        __syncthreads();
        if (tid < 64) xs[tid] = (double)x[(size_t)row*64 + tid];
        __syncthreads();
        double xn = 0.0;
        #pragma unroll 8
        for (int d = 0; d < 64; d++) xn += xs[d]*xs[d];
        double best = INFINITY; int bk = 1 << 30;
        for (int bb = 0; bb < 4; bb++) {        // 256 codes per batch
            __syncthreads();                    // cbS free for reuse
            #pragma unroll
            for (int k = 0; k < 16; k++)        // 64 KB coalesced: 16 float4/thread
                ((float4*)cbS)[k*256 + tid] = ((const float4*)cb)[bb*4096 + k*256 + tid];
            __syncthreads();
            int kcode = bb*256 + tid;
            const int t6 = tid & 63;
            double dot = 0.0, cn2 = 0.0;
            #pragma unroll 8
            for (int dd = 0; dd < 64; dd++) {
                int d = (dd + t6) & 63;         // rotation: 2 lanes/bank (free)
                double cv = (double)cbS[tid*64 + d];
                dot = fma(xs[d], cv, dot);
                cn2 = fma(cv, cv, cn2);
            }
            double dist = (xn - 2.0*dot) + cn2;
            if (dist < best || (dist == best && kcode < bk)) { best = dist; bk = kcode; }
        }
        bd[tid] = best; bi[tid] = bk;
        __syncthreads();
        for (int s = 128; s > 0; s >>= 1) {
            if (tid < s) {
                double od = bd[tid+s]; int ok = bi[tid+s];
                if (od < bd[tid] || (od == bd[tid] && ok < bi[tid])) { bd[tid] = od; bi[tid] = ok; }
            }
            __syncthreads();
        }
        int bestk = bi[0];
        if (bestk != oldk) {
            double part = 0.0;
            if (tid < 64) {
                float cn = cb[(size_t)bestk*64 + tid];
                float co = cb[(size_t)oldk*64 + tid];
                out[(size_t)row*64 + tid] = cn;
                double dn = (double)cn - xs[tid];
                double dl = (double)co - xs[tid];
                part = dn*dn - dl*dl;
            }
            __syncthreads();
            bd[tid] = part;
            __syncthreads();
            for (int s = 128; s > 0; s >>= 1) {
                if (tid < s) bd[tid] += bd[tid+s];
                __syncthreads();
            }
            if (tid == 0) deltaS += bd[0];
        }
    }
    __syncthreads();
    if (tid == 0) deltaP[b] = (float)deltaS;   // always written

    // ---- C: last block assembles the loss ----
    __syncthreads();
    if (tid == 0) {
        __threadfence();
        lastS = (atomicAdd(ticket, 1u) == 63u) ? 1u : 0u;
    }
    __syncthreads();
    if (lastS) {
        __threadfence();
        volatile const float* sp = sumsqP;
        volatile const float* dp = deltaP;
        volatile const float* p2 = partial2;
        float sq = sp[tid] + sp[256 + tid] + ((tid < 64) ? dp[tid] : 0.f);
        float es = 0.f;
        #pragma unroll
        for (int jj = 0; jj < 4; jj++) {
            int c = jj*256 + tid;
            es += fminf(fminf(p2[c], p2[1024 + c]), fminf(p2[2048 + c], p2[3072 + c]));
        }
        #pragma unroll
        for (int o = 32; o > 0; o >>= 1) { sq += __shfl_down(sq, o); es += __shfl_down(es, o); }
        if (lane == 0) { redS[w] = sq; redS2[w] = es; }
        __syncthreads();
        if (tid == 0) {
            float S = redS[0] + redS[1] + redS[2] + redS[3];
            float E = redS2[0] + redS2[1] + redS2[2] + redS2[3];
            out_loss[0] = 1.25f * (S / 2097152.0f) + 0.1f * (E / 1024.0f);
        }
    }
}

extern "C" void kernel_launch(void* const* d_in, const int* in_sizes, int n_in,
                              void* d_out, int out_size, void* d_ws, size_t ws_size,
                              hipStream_t stream) {
    const float* x  = (const float*)d_in[0];   // [32768, 64]
    const float* cb = (const float*)d_in[1];   // [1024, 64]
    float* out = (float*)d_out;                // [0,2097152): emb; [2097152]: loss

    char* ws = (char*)d_ws;
    unsigned* ticket     = (unsigned*)ws;                 // @0 (init by main block 0)
    float*    sumsqP     = (float*)(ws + 1024);           // 2 KB  [512]
    float*    deltaP     = (float*)(ws + 4096);           // 256 B [64]
    unsigned* flags      = (unsigned*)(ws + 8192);        // 128 KB [32768] tagged
    float*    partial2   = (float*)(ws + 139264);         // 16 KB [4][1024]
    float*    entPartial = (float*)(ws + 262144);         // 2 MB  [512][1024]

    vq_main<<<512, 512, 0, stream>>>(x, cb, out, entPartial, flags, sumsqP, ticket);
    vq_tail<<<64,  256, 0, stream>>>(x, cb, out, entPartial, flags, sumsqP, deltaP,
                                     partial2, ticket, out + 2097152);
}

// Round 16
// 128.405 us; speedup vs baseline: 1.0051x; 1.0051x over previous
//
#include <hip/hip_runtime.h>
#include <math.h>

#define NROWS 32768
#define NCODE 1024
#define GAP_THRESH 1.5e-4f  // exact fp32 gap; emulation err ~1e-5, np-ref rounding ~2e-5
#define FLAG_TAG_SHIFT 30   // flags[row]>>30==1 <=> ambiguous (rejects 0xAA poison AND 0)

typedef __attribute__((ext_vector_type(8))) short bf16x8;   // 8 bf16 = 4 VGPRs
typedef __attribute__((ext_vector_type(4))) float f32x4;    // MFMA acc

__device__ __forceinline__ unsigned short bf16_rne(float f) {
    unsigned u = __float_as_uint(f);
    unsigned r = u + 0x7FFFu + ((u >> 16) & 1u);
    return (unsigned short)(r >> 16);
}

// ---------------------------------------------------------------------------
// main: 512 blocks x 512 threads = 64 rows x ALL 1024 codes. Prep folded in,
// CONFLICT-FREE staging (r15 lesson: old quad assignment made every staging
// ds_write 8-way bank-conflicted, 3.1M conflicts). New assignment: wave w
// stages tile w; lane L holds code w*16+(L&15), dims hh*32+(L>>4)*8; each
// ds_write_b128 covers one q-block at qb + q*1024 + L*16 -> banks L*4%32,
// only the free 2-way alias. cn4 via shfl over the 4 gdim lanes x 2 halves.
// ---------------------------------------------------------------------------
__global__ __launch_bounds__(512, 4) void vq_main(
    const float* __restrict__ x, const float* __restrict__ cb,
    float* __restrict__ out, float* __restrict__ entPartial,
    unsigned* __restrict__ flags, float* __restrict__ sumsqP,
    unsigned* __restrict__ ticket)
{
    __shared__ __align__(16) unsigned char Bb[2][32768];
    __shared__ float cn4L[2][128];
    __shared__ unsigned scrE[1024];        // per-block per-code min dist (raw bits)
    __shared__ float mD1[128], mD2[128];   // [row 0..63][half 0..1]
    __shared__ int   mI1[128];
    __shared__ int   tokS[64];
    __shared__ float redS[8];

    const int tid = threadIdx.x;
    const int lane = tid & 63;
    const int wi = tid >> 6;         // 0..7
    const int g = wi >> 1;           // row group 0..3 (16 rows each)
    const int h = wi & 1;            // code half: ct tiles 4h..4h+3
    const int ln15 = lane & 15;
    const int q = lane >> 4;
    const int gdim = lane >> 4;      // staging dim-group 0..3
    const int row0 = blockIdx.x * 64;
    const int rot = blockIdx.x & 7;  // 8 chunks of 128 codes

    if (blockIdx.x == 0 && tid == 0) *ticket = 0u;

    // init scrE to +inf bits
    scrE[tid] = 0x7F800000u;
    scrE[512 + tid] = 0x7F800000u;

    // stage: lane L converts its 16 floats (code w*16+cl, dims hh*32+gdim*8)
    // into hi/lo frags of tile wi; all 4 ds_writes are q-block-aligned.
    auto stage = [&](int bufIdx, float4 a0, float4 a1, float4 b0, float4 b1) {
        unsigned char* qb = Bb[bufIdx] + wi*4096;
        float ss = 0.f;
        {
            float f[8] = {a0.x,a0.y,a0.z,a0.w,a1.x,a1.y,a1.z,a1.w};
            unsigned short h8[8] __attribute__((aligned(16)));
            unsigned short l8[8] __attribute__((aligned(16)));
            #pragma unroll
            for (int j = 0; j < 8; j++) {
                ss = fmaf(f[j], f[j], ss);
                unsigned short hi = bf16_rne(f[j]);
                h8[j] = hi;
                l8[j] = bf16_rne(f[j] - __uint_as_float((unsigned)hi << 16));
            }
            *(uint4*)(qb +    0 + lane*16) = *(const uint4*)h8;   // q0: hi dims 0-31
            *(uint4*)(qb + 2048 + lane*16) = *(const uint4*)l8;   // q2: lo dims 0-31
        }
        {
            float f[8] = {b0.x,b0.y,b0.z,b0.w,b1.x,b1.y,b1.z,b1.w};
            unsigned short h8[8] __attribute__((aligned(16)));
            unsigned short l8[8] __attribute__((aligned(16)));
            #pragma unroll
            for (int j = 0; j < 8; j++) {
                ss = fmaf(f[j], f[j], ss);
                unsigned short hi = bf16_rne(f[j]);
                h8[j] = hi;
                l8[j] = bf16_rne(f[j] - __uint_as_float((unsigned)hi << 16));
            }
            *(uint4*)(qb + 1024 + lane*16) = *(const uint4*)h8;   // q1: hi dims 32-63
            *(uint4*)(qb + 3072 + lane*16) = *(const uint4*)l8;   // q3: lo dims 32-63
        }
        ss += __shfl_xor(ss, 16);
        ss += __shfl_xor(ss, 32);        // full ||c||^2 (4 gdim lanes x both halves)
        if (lane < 16) cn4L[bufIdx][wi*16 + lane] = ss + 4.0f;
    };

    // preload chunk 'rot': lane's 16 floats of its staged code
    float4 p0, p1, p2, p3;
    {
        const float* cr = cb + (size_t)(rot*128 + wi*16 + ln15)*64 + gdim*8;
        p0 = *(const float4*)(cr);        p1 = *(const float4*)(cr + 4);
        p2 = *(const float4*)(cr + 32);   p3 = *(const float4*)(cr + 36);
    }

    // ---- A: 16 rows fp32 -> split-bf16 frags in regs; row norms via shfl ----
    bf16x8 Ah0, Ah1, Al0, Al1;
    float xnm4[4];
    {
        const float* xr = x + (size_t)(row0 + g*16 + ln15) * 64 + q * 8;
        float4 f0 = *(const float4*)xr;
        float4 f1 = *(const float4*)(xr + 4);
        float4 f2 = *(const float4*)(xr + 32);
        float4 f3 = *(const float4*)(xr + 36);
        float fa[8] = {f0.x,f0.y,f0.z,f0.w,f1.x,f1.y,f1.z,f1.w};
        float fb[8] = {f2.x,f2.y,f2.z,f2.w,f3.x,f3.y,f3.z,f3.w};
        unsigned short hh8[8] __attribute__((aligned(16)));
        unsigned short ll8[8] __attribute__((aligned(16)));
        unsigned short h28[8] __attribute__((aligned(16)));
        unsigned short l28[8] __attribute__((aligned(16)));
        float ss = 0.f;
        #pragma unroll
        for (int j = 0; j < 8; j++) {
            ss += fa[j]*fa[j] + fb[j]*fb[j];
            unsigned short hh = bf16_rne(fa[j]);
            hh8[j] = hh; ll8[j] = bf16_rne(fa[j] - __uint_as_float((unsigned)hh << 16));
            hh = bf16_rne(fb[j]);
            h28[j] = hh; l28[j] = bf16_rne(fb[j] - __uint_as_float((unsigned)hh << 16));
        }
        Ah0 = *(const bf16x8*)hh8; Al0 = *(const bf16x8*)ll8;
        Ah1 = *(const bf16x8*)h28; Al1 = *(const bf16x8*)l28;
        ss += __shfl_xor(ss, 16);
        ss += __shfl_xor(ss, 32);            // ||x_row(ln15)||^2
        #pragma unroll
        for (int r = 0; r < 4; r++)
            xnm4[r] = __shfl(ss, (q << 2) | r, 64) - 4.0f;  // xn(row q*4+r) - 4
    }

    // convert+write chunk 'rot' into Bb[0]
    stage(0, p0, p1, p2, p3);

    float d1[4], d2[4];
    int   i1[4];
    #pragma unroll
    for (int r = 0; r < 4; r++) { d1[r] = INFINITY; d2[r] = INFINITY; i1[r] = 0; }

    // ---- chunk loop: 8 chunks x 128 codes (rotated order) ----
    for (int s = 0; s < 8; s++) {
        __syncthreads();   // Bb[s&1]+cn4L[s&1] staged; Bb[nb] free
        const int cb_ = s & 1, nb = (s + 1) & 1;
        const int cphys = (s + rot) & 7;
        if (s < 7) {       // prefetch next raw chunk into regs
            const int cnx = (s + 1 + rot) & 7;
            const float* cr = cb + (size_t)(cnx*128 + wi*16 + ln15)*64 + gdim*8;
            p0 = *(const float4*)(cr);        p1 = *(const float4*)(cr + 4);
            p2 = *(const float4*)(cr + 32);   p3 = *(const float4*)(cr + 36);
        }
        const unsigned char* buf = Bb[cb_];
        #pragma unroll
        for (int lct = 0; lct < 4; lct++) {
            const int ct = 4*h + lct;                       // 0..7 within 128-code chunk
            const unsigned char* tb = buf + ct*4096;
            bf16x8 Bh0 = *(const bf16x8*)(tb +    0 + lane*16);
            bf16x8 Bh1 = *(const bf16x8*)(tb + 1024 + lane*16);
            bf16x8 Bl0 = *(const bf16x8*)(tb + 2048 + lane*16);
            bf16x8 Bl1 = *(const bf16x8*)(tb + 3072 + lane*16);
            float cn4v = cn4L[cb_][ct*16 + ln15];
            int kid = cphys*128 + ct*16 + ln15;
            f32x4 z = {0.f, 0.f, 0.f, 0.f};
            f32x4 acc0 = __builtin_amdgcn_mfma_f32_16x16x32_bf16(Ah0, Bh0, z, 0, 0, 0);
            f32x4 acc1 = __builtin_amdgcn_mfma_f32_16x16x32_bf16(Ah1, Bh1, z, 0, 0, 0);
            acc0 = __builtin_amdgcn_mfma_f32_16x16x32_bf16(Ah0, Bl0, acc0, 0, 0, 0);
            acc1 = __builtin_amdgcn_mfma_f32_16x16x32_bf16(Ah1, Bl1, acc1, 0, 0, 0);
            acc0 = __builtin_amdgcn_mfma_f32_16x16x32_bf16(Al0, Bh0, acc0, 0, 0, 0);
            acc1 = __builtin_amdgcn_mfma_f32_16x16x32_bf16(Al1, Bh1, acc1, 0, 0, 0);
            float cminv = INFINITY;
            #pragma unroll
            for (int r = 0; r < 4; r++) {
                float sdot = acc0[r] + acc1[r];
                float wv = fmaf(sdot, -2.0f, cn4v);   // 4 + cn - 2s  (>0)
                bool lt = wv < d1[r];
                d2[r] = lt ? d1[r] : fminf(d2[r], wv);
                i1[r] = lt ? kid   : i1[r];
                d1[r] = lt ? wv    : d1[r];
                cminv = fminf(cminv, wv + xnm4[r]);   // full dist (entropy)
            }
            cminv = fminf(cminv, __shfl_xor(cminv, 16));
            cminv = fminf(cminv, __shfl_xor(cminv, 32));   // min over wave's 16 rows
            if (q == lct) atomicMin(&scrE[kid], __float_as_uint(cminv));
        }
        if (s < 7) stage(nb, p0, p1, p2, p3);   // convert+write next chunk
    }
    __syncthreads();   // scrE complete; all compute done

    // ---- butterfly exact top-2 merge across the 16 code-column lanes ----
    #pragma unroll
    for (int d = 1; d < 16; d <<= 1) {
        #pragma unroll
        for (int r = 0; r < 4; r++) {
            float od1 = __shfl_xor(d1[r], d);
            int   oi1 = __shfl_xor(i1[r], d);
            float od2 = __shfl_xor(d2[r], d);
            bool take = (od1 < d1[r]) || (od1 == d1[r] && oi1 < i1[r]);
            float loser = take ? d1[r] : od1;
            d2[r] = fminf(fminf(d2[r], od2), loser);
            d1[r] = take ? od1 : d1[r];
            i1[r] = take ? oi1 : i1[r];
        }
    }
    if (ln15 == 0) {
        #pragma unroll
        for (int r = 0; r < 4; r++) {
            int idx = (g*16 + q*4 + r) * 2 + h;
            mD1[idx] = d1[r]; mI1[idx] = i1[r]; mD2[idx] = d2[r];
        }
    }
    __syncthreads();   // per-half candidates staged

    // ---- exact cross-half merge -> token + tagged ambiguity flag ----
    if (tid < 64) {
        float a1 = mD1[tid*2],   b1 = mD1[tid*2+1];
        int   ai = mI1[tid*2],   bi = mI1[tid*2+1];
        float a2 = mD2[tid*2],   b2 = mD2[tid*2+1];
        bool ta = (a1 < b1) || (a1 == b1 && ai < bi);
        float D1 = ta ? a1 : b1;
        int   I1 = ta ? ai : bi;
        float D2 = ta ? fminf(a2, b1) : fminf(b2, a1);
        tokS[tid] = I1;
        if (D2 - D1 < GAP_THRESH)
            flags[row0 + tid] = (1u << FLAG_TAG_SHIFT) | (unsigned)I1;
    }

    // ---- entropy partials: coalesced per-block row (always fully written) ----
    entPartial[(size_t)blockIdx.x * 1024 + tid]       = __uint_as_float(scrE[tid]);
    entPartial[(size_t)blockIdx.x * 1024 + 512 + tid] = __uint_as_float(scrE[512 + tid]);
    __syncthreads();   // tokS ready

    // ---- emb gather + sumsq -> sumsqP[block] ----
    {
        float acc2 = 0.f;
        #pragma unroll
        for (int uu = 0; uu < 2; uu++) {
            int u = uu*512 + tid;
            int row = u >> 4, c4 = u & 15;
            int tok = tokS[row];
            float4 c = ((const float4*)(cb + (size_t)tok*64))[c4];
            float4 xx = ((const float4*)(x + (size_t)(row0 + row)*64))[c4];
            ((float4*)(out + (size_t)(row0 + row)*64))[c4] = c;
            float dx = c.x-xx.x, dy = c.y-xx.y, dz = c.z-xx.z, dw = c.w-xx.w;
            acc2 += dx*dx + dy*dy + dz*dz + dw*dw;
        }
        #pragma unroll
        for (int o = 32; o > 0; o >>= 1) acc2 += __shfl_down(acc2, o);
        if (lane == 0) redS[wi] = acc2;
        __syncthreads();
        if (tid == 0) {
            float t = 0.f;
            #pragma unroll
            for (int w = 0; w < 8; w++) t += redS[w];
            sumsqP[blockIdx.x] = t;
        }
    }
}

// ---------------------------------------------------------------------------
// tail: 64 blocks x 256 threads. (r15 verbatim — components proven r13/r14)
// (A) coalesced entropy reduce -> partial2[4][1024].
// (B) flags scan + fp64 fixup with cb staged through LDS (coalesced).
// (C) last-ticket block assembles the loss.
// ---------------------------------------------------------------------------
__global__ __launch_bounds__(256) void vq_tail(
    const float* __restrict__ x, const float* __restrict__ cb,
    float* __restrict__ out, const float* __restrict__ entPartial,
    const unsigned* __restrict__ flags, const float* __restrict__ sumsqP,
    float* __restrict__ deltaP, float* __restrict__ partial2,
    unsigned* __restrict__ ticket, float* __restrict__ out_loss)
{
    __shared__ __align__(16) float cbS[16384];   // 64 KB: 256 codes x 64 dims
    __shared__ double xs[64];
    __shared__ double bd[256];
    __shared__ int    bi[256];
    __shared__ float  scrR[256];
    __shared__ int    listRow[32], listTok[32];
    __shared__ int    lcnt;
    __shared__ double deltaS;
    __shared__ unsigned lastS;
    __shared__ float redS[4], redS2[4];

    const int tid = threadIdx.x;
    const int lane = tid & 63;
    const int w = tid >> 6;
    const int b = blockIdx.x;

    if (tid == 0) { lcnt = 0; deltaS = 0.0; }

    // ---- A: entropy 512 block-rows -> 4 rowGroups (coalesced 256B reads) ----
    {
        int rg = b >> 4, cgp = b & 15;
        float m = INFINITY;
        #pragma unroll 8
        for (int i = 0; i < 32; i++)
            m = fminf(m, entPartial[(size_t)(rg*128 + w*32 + i)*1024 + cgp*64 + lane]);
        scrR[w*64 + lane] = m;
    }
    __syncthreads();
    if (w == 0) {
        float m = fminf(fminf(scrR[lane], scrR[64+lane]),
                        fminf(scrR[128+lane], scrR[192+lane]));
        partial2[(size_t)(b >> 4)*1024 + (b & 15)*64 + lane] = m;
    }

    // ---- B: scan tagged flags, compact, coalesced fp64 fixup ----
    #pragma unroll
    for (int u = 0; u < 2; u++) {
        int row = b*512 + u*256 + tid;
        unsigned f = flags[row];
        if ((f >> FLAG_TAG_SHIFT) == 1u) {     // rejects 0xAA poison (0b10) and 0
            int idx = atomicAdd(&lcnt, 1);
            if (idx < 32) { listRow[idx] = row; listTok[idx] = (int)(f & 1023u); }
        }
    }
    __syncthreads();
    int nfix = lcnt < 32 ? lcnt : 32;
    for (int i = 0; i < nfix; i++) {
        int row = listRow[i], oldk = listTok[i];
        __syncthreads();
        if (tid < 64) xs[tid] = (double)x[(size_t)row*64 + tid];
        __syncthreads();
        double xn = 0.0;
        #pragma unroll 8
        for (int d = 0; d < 64; d++) xn += xs[d]*xs[d];
        double best = INFINITY; int bk = 1 << 30;
        for (int bb = 0; bb < 4; bb++) {        // 256 codes per batch
            __syncthreads();                    // cbS free for reuse
            #pragma unroll
            for (int k = 0; k < 16; k++)        // 64 KB coalesced: 16 float4/thread
                ((float4*)cbS)[k*256 + tid] = ((const float4*)cb)[bb*4096 + k*256 + tid];
            __syncthreads();
            int kcode = bb*256 + tid;
            const int t6 = tid & 63;
            double dot = 0.0, cn2 = 0.0;
            #pragma unroll 8
            for (int dd = 0; dd < 64; dd++) {
                int d = (dd + t6) & 63;         // rotation: 2 lanes/bank (free)
                double cv = (double)cbS[tid*64 + d];
                dot = fma(xs[d], cv, dot);
                cn2 = fma(cv, cv, cn2);
            }
            double dist = (xn - 2.0*dot) + cn2;
            if (dist < best || (dist == best && kcode < bk)) { best = dist; bk = kcode; }
        }
        bd[tid] = best; bi[tid] = bk;
        __syncthreads();
        for (int s = 128; s > 0; s >>= 1) {
            if (tid < s) {
                double od = bd[tid+s]; int ok = bi[tid+s];
                if (od < bd[tid] || (od == bd[tid] && ok < bi[tid])) { bd[tid] = od; bi[tid] = ok; }
            }
            __syncthreads();
        }
        int bestk = bi[0];
        if (bestk != oldk) {
            double part = 0.0;
            if (tid < 64) {
                float cn = cb[(size_t)bestk*64 + tid];
                float co = cb[(size_t)oldk*64 + tid];
                out[(size_t)row*64 + tid] = cn;
                double dn = (double)cn - xs[tid];
                double dl = (double)co - xs[tid];
                part = dn*dn - dl*dl;
            }
            __syncthreads();
            bd[tid] = part;
            __syncthreads();
            for (int s = 128; s > 0; s >>= 1) {
                if (tid < s) bd[tid] += bd[tid+s];
                __syncthreads();
            }
            if (tid == 0) deltaS += bd[0];
        }
    }
    __syncthreads();
    if (tid == 0) deltaP[b] = (float)deltaS;   // always written

    // ---- C: last block assembles the loss ----
    __syncthreads();
    if (tid == 0) {
        __threadfence();
        lastS = (atomicAdd(ticket, 1u) == 63u) ? 1u : 0u;
    }
    __syncthreads();
    if (lastS) {
        __threadfence();
        volatile const float* sp = sumsqP;
        volatile const float* dp = deltaP;
        volatile const float* p2 = partial2;
        float sq = sp[tid] + sp[256 + tid] + ((tid < 64) ? dp[tid] : 0.f);
        float es = 0.f;
        #pragma unroll
        for (int jj = 0; jj < 4; jj++) {
            int c = jj*256 + tid;
            es += fminf(fminf(p2[c], p2[1024 + c]), fminf(p2[2048 + c], p2[3072 + c]));
        }
        #pragma unroll
        for (int o = 32; o > 0; o >>= 1) { sq += __shfl_down(sq, o); es += __shfl_down(es, o); }
        if (lane == 0) { redS[w] = sq; redS2[w] = es; }
        __syncthreads();
        if (tid == 0) {
            float S = redS[0] + redS[1] + redS[2] + redS[3];
            float E = redS2[0] + redS2[1] + redS2[2] + redS2[3];
            out_loss[0] = 1.25f * (S / 2097152.0f) + 0.1f * (E / 1024.0f);
        }
    }
}

extern "C" void kernel_launch(void* const* d_in, const int* in_sizes, int n_in,
                              void* d_out, int out_size, void* d_ws, size_t ws_size,
                              hipStream_t stream) {
    const float* x  = (const float*)d_in[0];   // [32768, 64]
    const float* cb = (const float*)d_in[1];   // [1024, 64]
    float* out = (float*)d_out;                // [0,2097152): emb; [2097152]: loss

    char* ws = (char*)d_ws;
    unsigned* ticket     = (unsigned*)ws;                 // @0 (init by main block 0)
    float*    sumsqP     = (float*)(ws + 1024);           // 2 KB  [512]
    float*    deltaP     = (float*)(ws + 4096);           // 256 B [64]
    unsigned* flags      = (unsigned*)(ws + 8192);        // 128 KB [32768] tagged
    float*    partial2   = (float*)(ws + 139264);         // 16 KB [4][1024]
    float*    entPartial = (float*)(ws + 262144);         // 2 MB  [512][1024]

    vq_main<<<512, 512, 0, stream>>>(x, cb, out, entPartial, flags, sumsqP, ticket);
    vq_tail<<<64,  256, 0, stream>>>(x, cb, out, entPartial, flags, sumsqP, deltaP,
                                     partial2, ticket, out + 2097152);
}

// Round 17
// 127.103 us; speedup vs baseline: 1.0154x; 1.0102x over previous
//
#include <hip/hip_runtime.h>
#include <math.h>

#define NROWS 32768
#define NCODE 1024
#define GAP_THRESH 1.5e-4f  // exact fp32 gap; emulation err ~1e-5, np-ref rounding ~2e-5
#define FLAG_TAG_SHIFT 30   // flags[row]>>30==1 <=> ambiguous (rejects 0xAA poison AND 0)

typedef __attribute__((ext_vector_type(8))) short bf16x8;   // 8 bf16 = 4 VGPRs
typedef __attribute__((ext_vector_type(4))) float f32x4;    // MFMA acc

__device__ __forceinline__ unsigned short bf16_rne(float f) {
    unsigned u = __float_as_uint(f);
    unsigned r = u + 0x7FFFu + ((u >> 16) & 1u);
    return (unsigned short)(r >> 16);
}

// ---------------------------------------------------------------------------
// main: 512 blocks x 512 threads = 64 rows x ALL 1024 codes. Prep folded in
// with conflict-free staging (r16, 0 conflicts). Entropy: per-block scrE ->
// global COMPLEMENT-KEY atomicMax(minK): stored = ~bits(dist). Real keys are
// > 0xBB000000 (dist < 1.5e13), so BOTH uninit states (0xAA poison and 0)
// act as -inf for max -> no init kernel needed. r14-vs-r16 A/B showed this
// atomic path beats the entPartial 2MB round-trip by ~14 us.
// ---------------------------------------------------------------------------
__global__ __launch_bounds__(512, 4) void vq_main(
    const float* __restrict__ x, const float* __restrict__ cb,
    float* __restrict__ out, unsigned* __restrict__ minK,
    unsigned* __restrict__ flags, float* __restrict__ sumsqP,
    unsigned* __restrict__ ticket)
{
    __shared__ __align__(16) unsigned char Bb[2][32768];
    __shared__ float cn4L[2][128];
    __shared__ unsigned scrE[1024];        // per-block per-code min dist (raw bits)
    __shared__ float mD1[128], mD2[128];   // [row 0..63][half 0..1]
    __shared__ int   mI1[128];
    __shared__ int   tokS[64];
    __shared__ float redS[8];

    const int tid = threadIdx.x;
    const int lane = tid & 63;
    const int wi = tid >> 6;         // 0..7
    const int g = wi >> 1;           // row group 0..3 (16 rows each)
    const int h = wi & 1;            // code half: ct tiles 4h..4h+3
    const int ln15 = lane & 15;
    const int q = lane >> 4;
    const int gdim = lane >> 4;      // staging dim-group 0..3
    const int row0 = blockIdx.x * 64;
    const int rot = blockIdx.x & 7;  // 8 chunks of 128 codes

    if (blockIdx.x == 0 && tid == 0) *ticket = 0u;

    // init scrE to +inf bits
    scrE[tid] = 0x7F800000u;
    scrE[512 + tid] = 0x7F800000u;

    // stage: lane L converts its 16 floats (code wi*16+cl, dims hh*32+gdim*8)
    // into hi/lo frags of tile wi; all 4 ds_writes are q-block-aligned
    // (banks L*4%32 -> only the free 2-way alias; r16-verified 0 conflicts).
    auto stage = [&](int bufIdx, float4 a0, float4 a1, float4 b0, float4 b1) {
        unsigned char* qb = Bb[bufIdx] + wi*4096;
        float ss = 0.f;
        {
            float f[8] = {a0.x,a0.y,a0.z,a0.w,a1.x,a1.y,a1.z,a1.w};
            unsigned short h8[8] __attribute__((aligned(16)));
            unsigned short l8[8] __attribute__((aligned(16)));
            #pragma unroll
            for (int j = 0; j < 8; j++) {
                ss = fmaf(f[j], f[j], ss);
                unsigned short hi = bf16_rne(f[j]);
                h8[j] = hi;
                l8[j] = bf16_rne(f[j] - __uint_as_float((unsigned)hi << 16));
            }
            *(uint4*)(qb +    0 + lane*16) = *(const uint4*)h8;   // q0: hi dims 0-31
            *(uint4*)(qb + 2048 + lane*16) = *(const uint4*)l8;   // q2: lo dims 0-31
        }
        {
            float f[8] = {b0.x,b0.y,b0.z,b0.w,b1.x,b1.y,b1.z,b1.w};
            unsigned short h8[8] __attribute__((aligned(16)));
            unsigned short l8[8] __attribute__((aligned(16)));
            #pragma unroll
            for (int j = 0; j < 8; j++) {
                ss = fmaf(f[j], f[j], ss);
                unsigned short hi = bf16_rne(f[j]);
                h8[j] = hi;
                l8[j] = bf16_rne(f[j] - __uint_as_float((unsigned)hi << 16));
            }
            *(uint4*)(qb + 1024 + lane*16) = *(const uint4*)h8;   // q1: hi dims 32-63
            *(uint4*)(qb + 3072 + lane*16) = *(const uint4*)l8;   // q3: lo dims 32-63
        }
        ss += __shfl_xor(ss, 16);
        ss += __shfl_xor(ss, 32);        // full ||c||^2 (4 gdim lanes x both halves)
        if (lane < 16) cn4L[bufIdx][wi*16 + lane] = ss + 4.0f;
    };

    // preload chunk 'rot': lane's 16 floats of its staged code
    float4 p0, p1, p2, p3;
    {
        const float* cr = cb + (size_t)(rot*128 + wi*16 + ln15)*64 + gdim*8;
        p0 = *(const float4*)(cr);        p1 = *(const float4*)(cr + 4);
        p2 = *(const float4*)(cr + 32);   p3 = *(const float4*)(cr + 36);
    }

    // ---- A: 16 rows fp32 -> split-bf16 frags in regs; row norms via shfl ----
    bf16x8 Ah0, Ah1, Al0, Al1;
    float xnm4[4];
    {
        const float* xr = x + (size_t)(row0 + g*16 + ln15) * 64 + q * 8;
        float4 f0 = *(const float4*)xr;
        float4 f1 = *(const float4*)(xr + 4);
        float4 f2 = *(const float4*)(xr + 32);
        float4 f3 = *(const float4*)(xr + 36);
        float fa[8] = {f0.x,f0.y,f0.z,f0.w,f1.x,f1.y,f1.z,f1.w};
        float fb[8] = {f2.x,f2.y,f2.z,f2.w,f3.x,f3.y,f3.z,f3.w};
        unsigned short hh8[8] __attribute__((aligned(16)));
        unsigned short ll8[8] __attribute__((aligned(16)));
        unsigned short h28[8] __attribute__((aligned(16)));
        unsigned short l28[8] __attribute__((aligned(16)));
        float ss = 0.f;
        #pragma unroll
        for (int j = 0; j < 8; j++) {
            ss += fa[j]*fa[j] + fb[j]*fb[j];
            unsigned short hh = bf16_rne(fa[j]);
            hh8[j] = hh; ll8[j] = bf16_rne(fa[j] - __uint_as_float((unsigned)hh << 16));
            hh = bf16_rne(fb[j]);
            h28[j] = hh; l28[j] = bf16_rne(fb[j] - __uint_as_float((unsigned)hh << 16));
        }
        Ah0 = *(const bf16x8*)hh8; Al0 = *(const bf16x8*)ll8;
        Ah1 = *(const bf16x8*)h28; Al1 = *(const bf16x8*)l28;
        ss += __shfl_xor(ss, 16);
        ss += __shfl_xor(ss, 32);            // ||x_row(ln15)||^2
        #pragma unroll
        for (int r = 0; r < 4; r++)
            xnm4[r] = __shfl(ss, (q << 2) | r, 64) - 4.0f;  // xn(row q*4+r) - 4
    }

    // convert+write chunk 'rot' into Bb[0]
    stage(0, p0, p1, p2, p3);

    float d1[4], d2[4];
    int   i1[4];
    #pragma unroll
    for (int r = 0; r < 4; r++) { d1[r] = INFINITY; d2[r] = INFINITY; i1[r] = 0; }

    // ---- chunk loop: 8 chunks x 128 codes (rotated order) ----
    for (int s = 0; s < 8; s++) {
        __syncthreads();   // Bb[s&1]+cn4L[s&1] staged; Bb[nb] free
        const int cb_ = s & 1, nb = (s + 1) & 1;
        const int cphys = (s + rot) & 7;
        if (s < 7) {       // prefetch next raw chunk into regs
            const int cnx = (s + 1 + rot) & 7;
            const float* cr = cb + (size_t)(cnx*128 + wi*16 + ln15)*64 + gdim*8;
            p0 = *(const float4*)(cr);        p1 = *(const float4*)(cr + 4);
            p2 = *(const float4*)(cr + 32);   p3 = *(const float4*)(cr + 36);
        }
        const unsigned char* buf = Bb[cb_];
        #pragma unroll
        for (int lct = 0; lct < 4; lct++) {
            const int ct = 4*h + lct;                       // 0..7 within 128-code chunk
            const unsigned char* tb = buf + ct*4096;
            bf16x8 Bh0 = *(const bf16x8*)(tb +    0 + lane*16);
            bf16x8 Bh1 = *(const bf16x8*)(tb + 1024 + lane*16);
            bf16x8 Bl0 = *(const bf16x8*)(tb + 2048 + lane*16);
            bf16x8 Bl1 = *(const bf16x8*)(tb + 3072 + lane*16);
            float cn4v = cn4L[cb_][ct*16 + ln15];
            int kid = cphys*128 + ct*16 + ln15;
            f32x4 z = {0.f, 0.f, 0.f, 0.f};
            f32x4 acc0 = __builtin_amdgcn_mfma_f32_16x16x32_bf16(Ah0, Bh0, z, 0, 0, 0);
            f32x4 acc1 = __builtin_amdgcn_mfma_f32_16x16x32_bf16(Ah1, Bh1, z, 0, 0, 0);
            acc0 = __builtin_amdgcn_mfma_f32_16x16x32_bf16(Ah0, Bl0, acc0, 0, 0, 0);
            acc1 = __builtin_amdgcn_mfma_f32_16x16x32_bf16(Ah1, Bl1, acc1, 0, 0, 0);
            acc0 = __builtin_amdgcn_mfma_f32_16x16x32_bf16(Al0, Bh0, acc0, 0, 0, 0);
            acc1 = __builtin_amdgcn_mfma_f32_16x16x32_bf16(Al1, Bh1, acc1, 0, 0, 0);
            float cminv = INFINITY;
            #pragma unroll
            for (int r = 0; r < 4; r++) {
                float sdot = acc0[r] + acc1[r];
                float wv = fmaf(sdot, -2.0f, cn4v);   // 4 + cn - 2s  (>0)
                bool lt = wv < d1[r];
                d2[r] = lt ? d1[r] : fminf(d2[r], wv);
                i1[r] = lt ? kid   : i1[r];
                d1[r] = lt ? wv    : d1[r];
                cminv = fminf(cminv, wv + xnm4[r]);   // full dist (entropy)
            }
            cminv = fminf(cminv, __shfl_xor(cminv, 16));
            cminv = fminf(cminv, __shfl_xor(cminv, 32));   // min over wave's 16 rows
            if (q == lct) atomicMin(&scrE[kid], __float_as_uint(cminv));
        }
        if (s < 7) stage(nb, p0, p1, p2, p3);   // convert+write next chunk
    }
    __syncthreads();   // scrE complete; all compute done

    // ---- butterfly exact top-2 merge across the 16 code-column lanes ----
    #pragma unroll
    for (int d = 1; d < 16; d <<= 1) {
        #pragma unroll
        for (int r = 0; r < 4; r++) {
            float od1 = __shfl_xor(d1[r], d);
            int   oi1 = __shfl_xor(i1[r], d);
            float od2 = __shfl_xor(d2[r], d);
            bool take = (od1 < d1[r]) || (od1 == d1[r] && oi1 < i1[r]);
            float loser = take ? d1[r] : od1;
            d2[r] = fminf(fminf(d2[r], od2), loser);
            d1[r] = take ? od1 : d1[r];
            i1[r] = take ? oi1 : i1[r];
        }
    }
    if (ln15 == 0) {
        #pragma unroll
        for (int r = 0; r < 4; r++) {
            int idx = (g*16 + q*4 + r) * 2 + h;
            mD1[idx] = d1[r]; mI1[idx] = i1[r]; mD2[idx] = d2[r];
        }
    }
    __syncthreads();   // per-half candidates staged

    // ---- exact cross-half merge -> token + tagged ambiguity flag ----
    if (tid < 64) {
        float a1 = mD1[tid*2],   b1 = mD1[tid*2+1];
        int   ai = mI1[tid*2],   bi = mI1[tid*2+1];
        float a2 = mD2[tid*2],   b2 = mD2[tid*2+1];
        bool ta = (a1 < b1) || (a1 == b1 && ai < bi);
        float D1 = ta ? a1 : b1;
        int   I1 = ta ? ai : bi;
        float D2 = ta ? fminf(a2, b1) : fminf(b2, a1);
        tokS[tid] = I1;
        if (D2 - D1 < GAP_THRESH)
            flags[row0 + tid] = (1u << FLAG_TAG_SHIFT) | (unsigned)I1;
    }

    // ---- entropy: filtered COMPLEMENT-KEY global atomicMax (init-free) ----
    {
        unsigned k0 = ~scrE[tid];          // > 0xBB000000 for any real dist
        if (k0 > minK[tid]) atomicMax(&minK[tid], k0);        // monotone; race benign
        unsigned k1 = ~scrE[512 + tid];
        if (k1 > minK[512 + tid]) atomicMax(&minK[512 + tid], k1);
    }
    __syncthreads();   // tokS ready

    // ---- emb gather + sumsq -> sumsqP[block] ----
    {
        float acc2 = 0.f;
        #pragma unroll
        for (int uu = 0; uu < 2; uu++) {
            int u = uu*512 + tid;
            int row = u >> 4, c4 = u & 15;
            int tok = tokS[row];
            float4 c = ((const float4*)(cb + (size_t)tok*64))[c4];
            float4 xx = ((const float4*)(x + (size_t)(row0 + row)*64))[c4];
            ((float4*)(out + (size_t)(row0 + row)*64))[c4] = c;
            float dx = c.x-xx.x, dy = c.y-xx.y, dz = c.z-xx.z, dw = c.w-xx.w;
            acc2 += dx*dx + dy*dy + dz*dz + dw*dw;
        }
        #pragma unroll
        for (int o = 32; o > 0; o >>= 1) acc2 += __shfl_down(acc2, o);
        if (lane == 0) redS[wi] = acc2;
        __syncthreads();
        if (tid == 0) {
            float t = 0.f;
            #pragma unroll
            for (int w = 0; w < 8; w++) t += redS[w];
            sumsqP[blockIdx.x] = t;
        }
    }
}

// ---------------------------------------------------------------------------
// tail: 64 blocks x 256 threads. No entPartial (r16 lesson: the 2MB
// round-trip cost ~14 us vs the atomic path).
// (A) flags scan + fp64 fixup with cb staged through LDS (r14-proven).
// (B) last-ticket block: entropy = sum ~minK[c]; sumsq = sumsqP + deltaP.
// ---------------------------------------------------------------------------
__global__ __launch_bounds__(256) void vq_tail(
    const float* __restrict__ x, const float* __restrict__ cb,
    float* __restrict__ out, const unsigned* __restrict__ minK,
    const unsigned* __restrict__ flags, const float* __restrict__ sumsqP,
    float* __restrict__ deltaP, unsigned* __restrict__ ticket,
    float* __restrict__ out_loss)
{
    __shared__ __align__(16) float cbS[16384];   // 64 KB: 256 codes x 64 dims
    __shared__ double xs[64];
    __shared__ double bd[256];
    __shared__ int    bi[256];
    __shared__ int    listRow[32], listTok[32];
    __shared__ int    lcnt;
    __shared__ double deltaS;
    __shared__ unsigned lastS;
    __shared__ float redS[4], redS2[4];

    const int tid = threadIdx.x;
    const int lane = tid & 63;
    const int w = tid >> 6;
    const int b = blockIdx.x;

    if (tid == 0) { lcnt = 0; deltaS = 0.0; }
    __syncthreads();

    // ---- A: scan tagged flags, compact, coalesced fp64 fixup ----
    #pragma unroll
    for (int u = 0; u < 2; u++) {
        int row = b*512 + u*256 + tid;
        unsigned f = flags[row];
        if ((f >> FLAG_TAG_SHIFT) == 1u) {     // rejects 0xAA poison (0b10) and 0
            int idx = atomicAdd(&lcnt, 1);
            if (idx < 32) { listRow[idx] = row; listTok[idx] = (int)(f & 1023u); }
        }
    }
    __syncthreads();
    int nfix = lcnt < 32 ? lcnt : 32;
    for (int i = 0; i < nfix; i++) {
        int row = listRow[i], oldk = listTok[i];
        __syncthreads();
        if (tid < 64) xs[tid] = (double)x[(size_t)row*64 + tid];
        __syncthreads();
        double xn = 0.0;
        #pragma unroll 8
        for (int d = 0; d < 64; d++) xn += xs[d]*xs[d];
        double best = INFINITY; int bk = 1 << 30;
        for (int bb = 0; bb < 4; bb++) {        // 256 codes per batch
            __syncthreads();                    // cbS free for reuse
            #pragma unroll
            for (int k = 0; k < 16; k++)        // 64 KB coalesced: 16 float4/thread
                ((float4*)cbS)[k*256 + tid] = ((const float4*)cb)[bb*4096 + k*256 + tid];
            __syncthreads();
            int kcode = bb*256 + tid;
            const int t6 = tid & 63;
            double dot = 0.0, cn2 = 0.0;
            #pragma unroll 8
            for (int dd = 0; dd < 64; dd++) {
                int d = (dd + t6) & 63;         // rotation: 2 lanes/bank (free)
                double cv = (double)cbS[tid*64 + d];
                dot = fma(xs[d], cv, dot);
                cn2 = fma(cv, cv, cn2);
            }
            double dist = (xn - 2.0*dot) + cn2;
            if (dist < best || (dist == best && kcode < bk)) { best = dist; bk = kcode; }
        }
        bd[tid] = best; bi[tid] = bk;
        __syncthreads();
        for (int s = 128; s > 0; s >>= 1) {
            if (tid < s) {
                double od = bd[tid+s]; int ok = bi[tid+s];
                if (od < bd[tid] || (od == bd[tid] && ok < bi[tid])) { bd[tid] = od; bi[tid] = ok; }
            }
            __syncthreads();
        }
        int bestk = bi[0];
        if (bestk != oldk) {
            double part = 0.0;
            if (tid < 64) {
                float cn = cb[(size_t)bestk*64 + tid];
                float co = cb[(size_t)oldk*64 + tid];
                out[(size_t)row*64 + tid] = cn;
                double dn = (double)cn - xs[tid];
                double dl = (double)co - xs[tid];
                part = dn*dn - dl*dl;
            }
            __syncthreads();
            bd[tid] = part;
            __syncthreads();
            for (int s = 128; s > 0; s >>= 1) {
                if (tid < s) bd[tid] += bd[tid+s];
                __syncthreads();
            }
            if (tid == 0) deltaS += bd[0];
        }
    }
    __syncthreads();
    if (tid == 0) deltaP[b] = (float)deltaS;   // always written

    // ---- B: last block assembles the loss ----
    __syncthreads();
    if (tid == 0) {
        __threadfence();
        lastS = (atomicAdd(ticket, 1u) == 63u) ? 1u : 0u;
    }
    __syncthreads();
    if (lastS) {
        __threadfence();
        volatile const float* sp = sumsqP;
        volatile const float* dp = deltaP;
        float sq = sp[tid] + sp[256 + tid] + ((tid < 64) ? dp[tid] : 0.f);
        float es = 0.f;
        #pragma unroll
        for (int jj = 0; jj < 4; jj++)
            es += __uint_as_float(~minK[jj*256 + tid]);   // decode complement keys
        #pragma unroll
        for (int o = 32; o > 0; o >>= 1) { sq += __shfl_down(sq, o); es += __shfl_down(es, o); }
        if (lane == 0) { redS[w] = sq; redS2[w] = es; }
        __syncthreads();
        if (tid == 0) {
            float S = redS[0] + redS[1] + redS[2] + redS[3];
            float E = redS2[0] + redS2[1] + redS2[2] + redS2[3];
            out_loss[0] = 1.25f * (S / 2097152.0f) + 0.1f * (E / 1024.0f);
        }
    }
}

extern "C" void kernel_launch(void* const* d_in, const int* in_sizes, int n_in,
                              void* d_out, int out_size, void* d_ws, size_t ws_size,
                              hipStream_t stream) {
    const float* x  = (const float*)d_in[0];   // [32768, 64]
    const float* cb = (const float*)d_in[1];   // [1024, 64]
    float* out = (float*)d_out;                // [0,2097152): emb; [2097152]: loss

    char* ws = (char*)d_ws;
    unsigned* ticket = (unsigned*)ws;                 // @0 (init by main block 0)
    float*    sumsqP = (float*)(ws + 1024);           // 2 KB  [512]
    float*    deltaP = (float*)(ws + 4096);           // 256 B [64]
    unsigned* minK   = (unsigned*)(ws + 6144);        // 4 KB  [1024] complement keys (init-free)
    unsigned* flags  = (unsigned*)(ws + 16384);       // 128 KB [32768] tagged

    vq_main<<<512, 512, 0, stream>>>(x, cb, out, minK, flags, sumsqP, ticket);
    vq_tail<<<64,  256, 0, stream>>>(x, cb, out, minK, flags, sumsqP, deltaP,
                                     ticket, out + 2097152);
}